// Round 1
// baseline (1251.458 us; speedup 1.0000x reference)
//
#include <hip/hip_runtime.h>
#include <cmath>
#include <stdint.h>

// ---------------------------------------------------------------------------
// VS_DiT_Block: B=1024, L=77, D=1024, H=16, DFF=4096
// Key simplifications:
//  * self-attn Lq=Lk=1  -> sa = (m1@wv.T+bv)@wo.T+bo
//  * cross-attn Lq=1    -> fold K/V projections into query side (qt trick)
// GEMMs in bf16 MFMA (16x16x32), everything else fp32.
// ---------------------------------------------------------------------------

#define DD 1024
#define NB 1024
#define LK 77
#define NHEAD 16
#define DFF_ 4096

typedef __bf16 bf16_t;
typedef __attribute__((ext_vector_type(8))) __bf16 bf16x8;
typedef __attribute__((ext_vector_type(4))) __bf16 bf16x4v;
typedef __attribute__((ext_vector_type(4))) float f32x4;

// ---------------- elementwise conversions ----------------
__global__ __launch_bounds__(256) void k_f2b(const float* __restrict__ in,
                                             bf16_t* __restrict__ out, int n) {
    int i = (blockIdx.x * 256 + threadIdx.x) * 4;
    if (i + 3 < n) {
        float4 v = *(const float4*)(in + i);
        bf16x4v o;
        o[0] = (bf16_t)v.x; o[1] = (bf16_t)v.y; o[2] = (bf16_t)v.z; o[3] = (bf16_t)v.w;
        *(bf16x4v*)(out + i) = o;
    }
}

__global__ __launch_bounds__(256) void k_silu_f2b(const float* __restrict__ in,
                                                  bf16_t* __restrict__ out, int n) {
    int i = (blockIdx.x * 256 + threadIdx.x) * 4;
    if (i + 3 < n) {
        float4 v = *(const float4*)(in + i);
        bf16x4v o;
        o[0] = (bf16_t)(v.x / (1.0f + __expf(-v.x)));
        o[1] = (bf16_t)(v.y / (1.0f + __expf(-v.y)));
        o[2] = (bf16_t)(v.z / (1.0f + __expf(-v.z)));
        o[3] = (bf16_t)(v.w / (1.0f + __expf(-v.w)));
        *(bf16x4v*)(out + i) = o;
    }
}

// transpose 1024x1024 fp32 -> bf16 (for ca_wk: wkT[d',n] = wk[n,d'])
__global__ __launch_bounds__(256) void k_transpose_f2b(const float* __restrict__ in,
                                                       bf16_t* __restrict__ out) {
    __shared__ float t[32][33];
    int lx = threadIdx.x & 31, ly = threadIdx.x >> 5;  // ly: 0..7
    int bx = blockIdx.x * 32, by = blockIdx.y * 32;
#pragma unroll
    for (int r = 0; r < 4; ++r)
        t[ly + r * 8][lx] = in[(size_t)(by + ly + r * 8) * DD + bx + lx];
    __syncthreads();
#pragma unroll
    for (int r = 0; r < 4; ++r)
        out[(size_t)(bx + ly + r * 8) * DD + by + lx] = (bf16_t)t[lx][ly + r * 8];
}

// ---------------- LayerNorm + modulation -> bf16 ----------------
// out = ln(x) * (1 + g) + be ; g = mod[:, gOff:gOff+D], be = mod[:, beOff:...]
__global__ __launch_bounds__(256) void k_ln_mod(const float* __restrict__ x,
                                                const float* __restrict__ mod,
                                                int gOff, int beOff,
                                                bf16_t* __restrict__ out) {
    const int b = blockIdx.x;
    const int t = threadIdx.x;
    const float4 v = *(const float4*)(x + (size_t)b * DD + t * 4);
    float s = v.x + v.y + v.z + v.w;
    float q = v.x * v.x + v.y * v.y + v.z * v.z + v.w * v.w;
#pragma unroll
    for (int o = 32; o > 0; o >>= 1) {
        s += __shfl_xor(s, o, 64);
        q += __shfl_xor(q, o, 64);
    }
    __shared__ float rs[4], rq[4];
    const int w = t >> 6;
    if ((t & 63) == 0) { rs[w] = s; rq[w] = q; }
    __syncthreads();
    const float S = rs[0] + rs[1] + rs[2] + rs[3];
    const float Q = rq[0] + rq[1] + rq[2] + rq[3];
    const float mean = S * (1.0f / DD);
    const float var = Q * (1.0f / DD) - mean * mean;
    const float rstd = rsqrtf(var + 1e-6f);
    const float* mrow = mod + (size_t)b * (9 * DD);
    const float4 g = *(const float4*)(mrow + gOff + t * 4);
    const float4 e = *(const float4*)(mrow + beOff + t * 4);
    bf16x4v o;
    o[0] = (bf16_t)((v.x - mean) * rstd * (1.0f + g.x) + e.x);
    o[1] = (bf16_t)((v.y - mean) * rstd * (1.0f + g.y) + e.y);
    o[2] = (bf16_t)((v.z - mean) * rstd * (1.0f + g.z) + e.z);
    o[3] = (bf16_t)((v.w - mean) * rstd * (1.0f + g.w) + e.w);
    *(bf16x4v*)(out + (size_t)b * DD + t * 4) = o;
}

// ---------------- generic bf16 MFMA GEMM:  C = epi(A @ W^T + bias) ----------
// A: (M,K) bf16 row-major (lda), W: (N,K) bf16 row-major (ldw).
// blockIdx.z = head batch with element offsets; tile 128 x BN, BK=32, 4 waves.
template <int BN, bool GELU_E, bool RESID, bool WF32, bool WB16>
__global__ __launch_bounds__(256) void k_gemm(
    const bf16_t* __restrict__ A, int lda, int aHeadOff,
    const bf16_t* __restrict__ W, int ldw, int wHeadOff,
    const float* __restrict__ bias, int biasHeadOff,
    float* __restrict__ Cf, bf16_t* __restrict__ Cb, int ldc, int cHeadOff,
    const float* __restrict__ res, int ldres,
    const float* __restrict__ am, int ldam,
    int K) {
    constexpr int BM = 128, BK = 32;
    const int z = blockIdx.z;
    A += (size_t)z * aHeadOff;
    W += (size_t)z * wHeadOff;
    const float* biasz = bias ? bias + (size_t)z * biasHeadOff : nullptr;
    const size_t coff = (size_t)z * cHeadOff;

    __shared__ bf16_t As[BM * BK];
    __shared__ bf16_t Bs[BN * BK];

    const int tid = threadIdx.x;
    const int wave = tid >> 6, lane = tid & 63;
    const int m0 = blockIdx.y * BM, n0 = blockIdx.x * BN;
    const int wm = (wave >> 1) * 64;
    constexpr int WN = (BN == 128) ? 64 : 32;
    const int wn = (wave & 1) * WN;
    constexpr int FN = WN / 16;

    f32x4 acc[4][FN];
#pragma unroll
    for (int i = 0; i < 4; ++i)
#pragma unroll
        for (int j = 0; j < FN; ++j) acc[i][j] = {0.f, 0.f, 0.f, 0.f};

    const int lrow = lane & 15;
    const int lk8 = (lane >> 4) * 8;

    for (int k0 = 0; k0 < K; k0 += BK) {
        // fetch tiles into registers (reg-staged: safest correct baseline)
        const int c0 = tid, c1 = tid + 256;
        bf16x8 ta0 = *(const bf16x8*)(A + (size_t)(m0 + (c0 >> 2)) * lda + k0 + (c0 & 3) * 8);
        bf16x8 ta1 = *(const bf16x8*)(A + (size_t)(m0 + (c1 >> 2)) * lda + k0 + (c1 & 3) * 8);
        bf16x8 tb0 = *(const bf16x8*)(W + (size_t)(n0 + (c0 >> 2)) * ldw + k0 + (c0 & 3) * 8);
        bf16x8 tb1;
        if constexpr (BN == 128)
            tb1 = *(const bf16x8*)(W + (size_t)(n0 + (c1 >> 2)) * ldw + k0 + (c1 & 3) * 8);

        __syncthreads();  // previous iteration's LDS reads done
        *(bf16x8*)(As + c0 * 8) = ta0;
        *(bf16x8*)(As + c1 * 8) = ta1;
        *(bf16x8*)(Bs + c0 * 8) = tb0;
        if constexpr (BN == 128) *(bf16x8*)(Bs + c1 * 8) = tb1;
        __syncthreads();  // tiles visible

        bf16x8 af[4], bfr[FN];
#pragma unroll
        for (int i = 0; i < 4; ++i)
            af[i] = *(const bf16x8*)(As + (wm + i * 16 + lrow) * BK + lk8);
#pragma unroll
        for (int j = 0; j < FN; ++j)
            bfr[j] = *(const bf16x8*)(Bs + (wn + j * 16 + lrow) * BK + lk8);
#pragma unroll
        for (int i = 0; i < 4; ++i)
#pragma unroll
            for (int j = 0; j < FN; ++j)
                acc[i][j] = __builtin_amdgcn_mfma_f32_16x16x32_bf16(af[i], bfr[j], acc[i][j], 0, 0, 0);
    }

    // epilogue: C/D layout col=lane&15, row=(lane>>4)*4+e  [verified m89/m91]
    const int r4 = (lane >> 4) * 4;
    const int cc = lane & 15;
#pragma unroll
    for (int i = 0; i < 4; ++i) {
#pragma unroll
        for (int j = 0; j < FN; ++j) {
            const int col = n0 + wn + j * 16 + cc;
            const float bv = biasz ? biasz[col] : 0.0f;
#pragma unroll
            for (int e = 0; e < 4; ++e) {
                const int row = m0 + wm + i * 16 + r4 + e;
                float v = acc[i][j][e] + bv;
                if constexpr (GELU_E) v = 0.5f * v * (1.0f + erff(v * 0.70710678118654752f));
                const size_t cidx = coff + (size_t)row * ldc + col;
                if constexpr (RESID) {
                    Cf[cidx] = res[(size_t)row * ldres + col] + am[(size_t)row * ldam + col] * v;
                } else {
                    if constexpr (WF32) Cf[cidx] = v;
                    if constexpr (WB16) Cb[cidx] = (bf16_t)v;
                }
            }
        }
    }
}

// ---------------- q·bk per head ----------------
__global__ __launch_bounds__(64) void k_qbk(const bf16_t* __restrict__ q,
                                            const float* __restrict__ bk,
                                            float* __restrict__ qbk) {
    const int b = blockIdx.x, lane = threadIdx.x;
#pragma unroll 1
    for (int h = 0; h < NHEAD; ++h) {
        float v = (float)q[(size_t)b * DD + h * 64 + lane] * bk[h * 64 + lane];
#pragma unroll
        for (int o = 32; o > 0; o >>= 1) v += __shfl_xor(v, o, 64);
        if (lane == 0) qbk[(size_t)b * NHEAD + h] = v;
    }
}

// ---------------- cross-attn scores + softmax ----------------
// score[b,h,l] = (qt[b,h,:]·ctx[b,l,:] + qbk[b,h]) / 8 ; softmax over l -> p
__global__ __launch_bounds__(256) void k_ca_scores(
    const bf16_t* __restrict__ qt, const float* __restrict__ qbk,
    const float* __restrict__ ctx, const unsigned char* __restrict__ mask,
    float* __restrict__ p) {
    constexpr int QS = DD + 8;  // padded strides (bank-conflict free)
    constexpr int CS = DD + 8;
    __shared__ unsigned short qlds[NHEAD * QS];
    __shared__ float clds[4 * CS];
    __shared__ float slds[NHEAD * 80];
    __shared__ float plds[4 * NHEAD * 4];  // [dq][h][lc]

    const int b = blockIdx.x;
    const int t = threadIdx.x;
    const unsigned short* qg = (const unsigned short*)(qt + (size_t)b * (NHEAD * DD));
    for (int e = t; e < NHEAD * DD; e += 256) {
        int h = e >> 10, d = e & (DD - 1);
        qlds[h * QS + d] = qg[e];
    }

    const int h = t & 15;
    const int lc = (t >> 4) & 3;
    const int dq = t >> 6;

    for (int c0 = 0; c0 < LK; c0 += 4) {
        __syncthreads();
        {  // stage 4 context rows
            int i = t >> 6;
            int dcol = (t & 63) * 16;
            int l = c0 + i;
            if (l < LK) {
                const float* src = ctx + ((size_t)b * LK + l) * DD + dcol;
                float* dst = clds + i * CS + dcol;
#pragma unroll
                for (int u = 0; u < 4; ++u) *(f32x4*)(dst + u * 4) = *(const f32x4*)(src + u * 4);
            }
        }
        __syncthreads();
        int l = c0 + lc;
        float part = 0.0f;
        if (l < LK) {
            const unsigned short* qr = qlds + h * QS + dq * 256;
            const float* cr = clds + lc * CS + dq * 256;
#pragma unroll 4
            for (int d = 0; d < 256; d += 8) {
                bf16x8 qv = *(const bf16x8*)(qr + d);
                f32x4 ca = *(const f32x4*)(cr + d);
                f32x4 cb = *(const f32x4*)(cr + d + 4);
                part += (float)qv[0] * ca.x + (float)qv[1] * ca.y + (float)qv[2] * ca.z +
                        (float)qv[3] * ca.w + (float)qv[4] * cb.x + (float)qv[5] * cb.y +
                        (float)qv[6] * cb.z + (float)qv[7] * cb.w;
            }
        }
        plds[(dq * NHEAD + h) * 4 + lc] = part;
        __syncthreads();
        if (t < 64) {
            int hh = t & 15, ll = t >> 4;
            int lg = c0 + ll;
            if (lg < LK) {
                float s = plds[(0 * NHEAD + hh) * 4 + ll] + plds[(1 * NHEAD + hh) * 4 + ll] +
                          plds[(2 * NHEAD + hh) * 4 + ll] + plds[(3 * NHEAD + hh) * 4 + ll];
                s = (s + qbk[(size_t)b * NHEAD + hh]) * 0.125f;
                if (mask[(size_t)b * LK + lg]) s = -1.0e9f;
                slds[hh * 80 + lg] = s;
            }
        }
    }
    __syncthreads();
    if (t < NHEAD) {
        float mx = -3.0e38f;
#pragma unroll 1
        for (int l2 = 0; l2 < LK; ++l2) mx = fmaxf(mx, slds[t * 80 + l2]);
        float sum = 0.0f;
#pragma unroll 1
        for (int l2 = 0; l2 < LK; ++l2) {
            float e2 = __expf(slds[t * 80 + l2] - mx);
            slds[t * 80 + l2] = e2;
            sum += e2;
        }
        float inv = 1.0f / sum;
#pragma unroll 1
        for (int l2 = 0; l2 < LK; ++l2)
            p[((size_t)b * NHEAD + t) * LK + l2] = slds[t * 80 + l2] * inv;
    }
}

// ---------------- cross-attn mix: mixed[b,h,:] = sum_l p[b,h,l] * ctx[b,l,:]
__global__ __launch_bounds__(256) void k_ca_mix(const float* __restrict__ p,
                                                const float* __restrict__ ctx,
                                                bf16_t* __restrict__ mixed) {
    __shared__ float plds[NHEAD * LK];
    __shared__ float clds[4 * DD];
    const int b = blockIdx.x;
    const int t = threadIdx.x;
    for (int e = t; e < NHEAD * LK; e += 256) plds[e] = p[(size_t)b * NHEAD * LK + e];
    const int h = t >> 4, dseg = t & 15;
    f32x4 acc4[16];
#pragma unroll
    for (int j = 0; j < 16; ++j) acc4[j] = {0.f, 0.f, 0.f, 0.f};
    for (int c0 = 0; c0 < LK; c0 += 4) {
        __syncthreads();
        {
            int i = t >> 6;
            int dcol = (t & 63) * 16;
            int l = c0 + i;
            if (l < LK) {
                const float* src = ctx + ((size_t)b * LK + l) * DD + dcol;
                float* dst = clds + i * DD + dcol;
#pragma unroll
                for (int u = 0; u < 4; ++u) *(f32x4*)(dst + u * 4) = *(const f32x4*)(src + u * 4);
            }
        }
        __syncthreads();
#pragma unroll
        for (int lc2 = 0; lc2 < 4; ++lc2) {
            int l = c0 + lc2;
            if (l < LK) {
                float pl = plds[h * LK + l];
                const float* cr = clds + lc2 * DD + dseg * 4;
#pragma unroll
                for (int j = 0; j < 16; ++j) {
                    f32x4 cv = *(const f32x4*)(cr + j * 64);
                    acc4[j].x += pl * cv.x;
                    acc4[j].y += pl * cv.y;
                    acc4[j].z += pl * cv.z;
                    acc4[j].w += pl * cv.w;
                }
            }
        }
    }
    bf16_t* orow = mixed + ((size_t)b * NHEAD + h) * DD + dseg * 4;
#pragma unroll
    for (int j = 0; j < 16; ++j) {
        bf16x4v o;
        o[0] = (bf16_t)acc4[j].x; o[1] = (bf16_t)acc4[j].y;
        o[2] = (bf16_t)acc4[j].z; o[3] = (bf16_t)acc4[j].w;
        *(bf16x4v*)(orow + j * 64) = o;
    }
}

// ---------------------------------------------------------------------------
extern "C" void kernel_launch(void* const* d_in, const int* in_sizes, int n_in,
                              void* d_out, int out_size, void* d_ws, size_t ws_size,
                              hipStream_t stream) {
    const float* x = (const float*)d_in[0];
    const float* temb = (const float*)d_in[1];
    const float* ctx = (const float*)d_in[2];
    const unsigned char* mask = (const unsigned char*)d_in[3];
    const float* w_mod = (const float*)d_in[4];
    const float* b_mod = (const float*)d_in[5];
    const float* sa_wv = (const float*)d_in[10];
    const float* sa_bv = (const float*)d_in[11];
    const float* sa_wo = (const float*)d_in[12];
    const float* sa_bo = (const float*)d_in[13];
    const float* ca_wq = (const float*)d_in[14];
    const float* ca_bq = (const float*)d_in[15];
    const float* ca_wk = (const float*)d_in[16];
    const float* ca_bk = (const float*)d_in[17];
    const float* ca_wv = (const float*)d_in[18];
    const float* ca_bv = (const float*)d_in[19];
    const float* ca_wo = (const float*)d_in[20];
    const float* ca_bo = (const float*)d_in[21];
    const float* w1 = (const float*)d_in[22];
    const float* b1 = (const float*)d_in[23];
    const float* w2 = (const float*)d_in[24];
    const float* b2 = (const float*)d_in[25];
    const float* w3 = (const float*)d_in[26];
    const float* b3 = (const float*)d_in[27];

    char* ws = (char*)d_ws;
    size_t off = 0;
    auto alloc = [&](size_t bytes) -> void* {
        void* pp = ws + off;
        off += (bytes + 255) & ~(size_t)255;
        return pp;
    };
    bf16_t* w_mod_b = (bf16_t*)alloc((size_t)9 * DD * DD * 2);
    bf16_t* sa_wv_b = (bf16_t*)alloc((size_t)DD * DD * 2);
    bf16_t* sa_wo_b = (bf16_t*)alloc((size_t)DD * DD * 2);
    bf16_t* ca_wq_b = (bf16_t*)alloc((size_t)DD * DD * 2);
    bf16_t* ca_wv_b = (bf16_t*)alloc((size_t)DD * DD * 2);
    bf16_t* ca_wo_b = (bf16_t*)alloc((size_t)DD * DD * 2);
    bf16_t* wkT_b = (bf16_t*)alloc((size_t)DD * DD * 2);
    bf16_t* w1_b = (bf16_t*)alloc((size_t)DFF_ * DD * 2);
    bf16_t* w2_b = (bf16_t*)alloc((size_t)DFF_ * DFF_ * 2);
    bf16_t* w3_b = (bf16_t*)alloc((size_t)DD * DFF_ * 2);
    bf16_t* tb = (bf16_t*)alloc((size_t)NB * DD * 2);
    float* mod_f = (float*)alloc((size_t)NB * 9 * DD * 4);
    bf16_t* m_b = (bf16_t*)alloc((size_t)NB * DD * 2);
    bf16_t* vsa_b = (bf16_t*)alloc((size_t)NB * DD * 2);
    float* x1 = (float*)alloc((size_t)NB * DD * 4);
    float* x2 = (float*)alloc((size_t)NB * DD * 4);
    bf16_t* q_b = (bf16_t*)alloc((size_t)NB * DD * 2);
    bf16_t* qt_b = (bf16_t*)alloc((size_t)NB * NHEAD * DD * 2);
    float* qbk_f = (float*)alloc((size_t)NB * NHEAD * 4);
    float* p_f = (float*)alloc((size_t)NB * NHEAD * LK * 4);
    bf16_t* oh_b = (bf16_t*)alloc((size_t)NB * DD * 2);
    bf16_t* h1_b = (bf16_t*)alloc((size_t)NB * DFF_ * 2);
    bf16_t* h2_b = (bf16_t*)alloc((size_t)NB * DFF_ * 2);
    bf16_t* mixed_b = qt_b;  // alias: qt dead after scores, mix written after
    (void)n_in; (void)in_sizes; (void)out_size; (void)ws_size;

    dim3 blk(256);
    // weight conversions
    k_f2b<<<9 * DD * DD / 1024, blk, 0, stream>>>(w_mod, w_mod_b, 9 * DD * DD);
    k_f2b<<<DD * DD / 1024, blk, 0, stream>>>(sa_wv, sa_wv_b, DD * DD);
    k_f2b<<<DD * DD / 1024, blk, 0, stream>>>(sa_wo, sa_wo_b, DD * DD);
    k_f2b<<<DD * DD / 1024, blk, 0, stream>>>(ca_wq, ca_wq_b, DD * DD);
    k_f2b<<<DD * DD / 1024, blk, 0, stream>>>(ca_wv, ca_wv_b, DD * DD);
    k_f2b<<<DD * DD / 1024, blk, 0, stream>>>(ca_wo, ca_wo_b, DD * DD);
    k_f2b<<<DFF_ * DD / 1024, blk, 0, stream>>>(w1, w1_b, DFF_ * DD);
    k_f2b<<<DFF_ * DFF_ / 1024, blk, 0, stream>>>(w2, w2_b, DFF_ * DFF_);
    k_f2b<<<DFF_ * DD / 1024, blk, 0, stream>>>(w3, w3_b, DFF_ * DD);
    k_transpose_f2b<<<dim3(32, 32), blk, 0, stream>>>(ca_wk, wkT_b);
    k_silu_f2b<<<NB * DD / 1024, blk, 0, stream>>>(temb, tb, NB * DD);

    // mod = silu(t_emb) @ w_mod.T + b_mod   (fp32 out)
    k_gemm<128, false, false, true, false><<<dim3(9 * DD / 128, NB / 128, 1), blk, 0, stream>>>(
        tb, DD, 0, w_mod_b, DD, 0, b_mod, 0, mod_f, nullptr, 9 * DD, 0, nullptr, 0, nullptr, 0, DD);

    // m1 = ln(x)*(1+g1)+be1
    k_ln_mod<<<NB, blk, 0, stream>>>(x, mod_f, 0 * DD, 1 * DD, m_b);
    // sa = (m1@wv.T+bv)@wo.T+bo ; x1 = x + a1*sa
    k_gemm<128, false, false, false, true><<<dim3(8, 8, 1), blk, 0, stream>>>(
        m_b, DD, 0, sa_wv_b, DD, 0, sa_bv, 0, nullptr, vsa_b, DD, 0, nullptr, 0, nullptr, 0, DD);
    k_gemm<128, false, true, true, false><<<dim3(8, 8, 1), blk, 0, stream>>>(
        vsa_b, DD, 0, sa_wo_b, DD, 0, sa_bo, 0, x1, nullptr, DD, 0, x, DD, mod_f + 2 * DD, 9 * DD, DD);

    // m2; q = m2@wq.T+bq
    k_ln_mod<<<NB, blk, 0, stream>>>(x1, mod_f, 3 * DD, 4 * DD, m_b);
    k_gemm<128, false, false, false, true><<<dim3(8, 8, 1), blk, 0, stream>>>(
        m_b, DD, 0, ca_wq_b, DD, 0, ca_bq, 0, nullptr, q_b, DD, 0, nullptr, 0, nullptr, 0, DD);
    // qt[b,h,:] = q_head @ wk_h  (16 batched GEMMs, K=64)
    k_gemm<128, false, false, false, true><<<dim3(8, 8, 16), blk, 0, stream>>>(
        q_b, DD, 64, wkT_b, DD, 64, nullptr, 0, nullptr, qt_b, NHEAD * DD, DD, nullptr, 0, nullptr, 0, 64);
    k_qbk<<<NB, 64, 0, stream>>>(q_b, ca_bk, qbk_f);
    k_ca_scores<<<NB, blk, 0, stream>>>(qt_b, qbk_f, ctx, mask, p_f);
    k_ca_mix<<<NB, blk, 0, stream>>>(p_f, ctx, mixed_b);
    // out_head[b,h*64:+64] = wv_h @ mixed[b,h,:] + bv_h  (16 batched, N=64)
    k_gemm<64, false, false, false, true><<<dim3(1, 8, 16), blk, 0, stream>>>(
        mixed_b, NHEAD * DD, DD, ca_wv_b, DD, 64 * DD, ca_bv, 64, nullptr, oh_b, DD, 64,
        nullptr, 0, nullptr, 0, DD);
    // ca = out_head@wo.T+bo ; x2 = x1 + a2*ca
    k_gemm<128, false, true, true, false><<<dim3(8, 8, 1), blk, 0, stream>>>(
        oh_b, DD, 0, ca_wo_b, DD, 0, ca_bo, 0, x2, nullptr, DD, 0, x1, DD, mod_f + 5 * DD, 9 * DD, DD);

    // m3; FFN
    k_ln_mod<<<NB, blk, 0, stream>>>(x2, mod_f, 6 * DD, 7 * DD, m_b);
    k_gemm<128, true, false, false, true><<<dim3(DFF_ / 128, 8, 1), blk, 0, stream>>>(
        m_b, DD, 0, w1_b, DD, 0, b1, 0, nullptr, h1_b, DFF_, 0, nullptr, 0, nullptr, 0, DD);
    k_gemm<128, true, false, false, true><<<dim3(DFF_ / 128, 8, 1), blk, 0, stream>>>(
        h1_b, DFF_, 0, w2_b, DFF_, 0, b2, 0, nullptr, h2_b, DFF_, 0, nullptr, 0, nullptr, 0, DFF_);
    // out = x2 + a3 * (h2@w3.T + b3)
    k_gemm<128, false, true, true, false><<<dim3(8, 8, 1), blk, 0, stream>>>(
        h2_b, DFF_, 0, w3_b, DFF_, 0, b3, 0, (float*)d_out, nullptr, DD, 0, x2, DD,
        mod_f + 8 * DD, 9 * DD, DFF_);
}

// Round 2
// 1192.227 us; speedup vs baseline: 1.0497x; 1.0497x over previous
//
#include <hip/hip_runtime.h>
#include <cmath>
#include <stdint.h>

// ---------------------------------------------------------------------------
// VS_DiT_Block: B=1024, L=77, D=1024, H=16, DFF=4096
//  * self-attn Lq=Lk=1  -> sa = (m1@wv.T+bv)@wo.T+bo
//  * cross-attn Lq=1    -> fold K/V projections into query side (qt trick)
//  * R2: global_load_lds GEMM staging (m97 structure), 64x64/64x128 tiles,
//        fused single-pass online-softmax cross-attention (bf16 ctx in LDS),
//        merged weight-conversion kernel.
// ---------------------------------------------------------------------------

#define DD 1024
#define NB 1024
#define LK 77
#define NHEAD 16
#define DFF_ 4096

typedef __bf16 bf16_t;
typedef __attribute__((ext_vector_type(8))) __bf16 bf16x8;
typedef __attribute__((ext_vector_type(4))) __bf16 bf16x4v;
typedef __attribute__((ext_vector_type(4))) float f32x4;

__device__ __forceinline__ void gload16(const bf16_t* g, bf16_t* l) {
    __builtin_amdgcn_global_load_lds(
        (const __attribute__((address_space(1))) void*)g,
        (__attribute__((address_space(3))) void*)l, 16, 0, 0);
}

// ---------------- merged fp32 -> bf16 conversions (1M-element units) -------
struct ConvTab {
    const float* src[40];
    bf16_t* dst[40];
    int silu[40];
};

__global__ __launch_bounds__(256) void k_conv_all(ConvTab tab) {
    const int u = blockIdx.x >> 10;
    const int i = ((blockIdx.x & 1023) * 256 + threadIdx.x) * 4;
    float4 v = *(const float4*)(tab.src[u] + i);
    if (tab.silu[u]) {
        v.x = v.x / (1.0f + __expf(-v.x));
        v.y = v.y / (1.0f + __expf(-v.y));
        v.z = v.z / (1.0f + __expf(-v.z));
        v.w = v.w / (1.0f + __expf(-v.w));
    }
    bf16x4v o;
    o[0] = (bf16_t)v.x; o[1] = (bf16_t)v.y; o[2] = (bf16_t)v.z; o[3] = (bf16_t)v.w;
    *(bf16x4v*)(tab.dst[u] + i) = o;
}

// transpose 1024x1024 fp32 -> bf16 (for ca_wk: wkT[d',n] = wk[n,d'])
__global__ __launch_bounds__(256) void k_transpose_f2b(const float* __restrict__ in,
                                                       bf16_t* __restrict__ out) {
    __shared__ float t[32][33];
    int lx = threadIdx.x & 31, ly = threadIdx.x >> 5;
    int bx = blockIdx.x * 32, by = blockIdx.y * 32;
#pragma unroll
    for (int r = 0; r < 4; ++r)
        t[ly + r * 8][lx] = in[(size_t)(by + ly + r * 8) * DD + bx + lx];
    __syncthreads();
#pragma unroll
    for (int r = 0; r < 4; ++r)
        out[(size_t)(bx + ly + r * 8) * DD + by + lx] = (bf16_t)t[lx][ly + r * 8];
}

// ---------------- LayerNorm + modulation -> bf16 ----------------
__global__ __launch_bounds__(256) void k_ln_mod(const float* __restrict__ x,
                                                const float* __restrict__ mod,
                                                int gOff, int beOff,
                                                bf16_t* __restrict__ out) {
    const int b = blockIdx.x;
    const int t = threadIdx.x;
    const float4 v = *(const float4*)(x + (size_t)b * DD + t * 4);
    float s = v.x + v.y + v.z + v.w;
    float q = v.x * v.x + v.y * v.y + v.z * v.z + v.w * v.w;
#pragma unroll
    for (int o = 32; o > 0; o >>= 1) {
        s += __shfl_xor(s, o, 64);
        q += __shfl_xor(q, o, 64);
    }
    __shared__ float rs[4], rq[4];
    const int w = t >> 6;
    if ((t & 63) == 0) { rs[w] = s; rq[w] = q; }
    __syncthreads();
    const float S = rs[0] + rs[1] + rs[2] + rs[3];
    const float Q = rq[0] + rq[1] + rq[2] + rq[3];
    const float mean = S * (1.0f / DD);
    const float var = Q * (1.0f / DD) - mean * mean;
    const float rstd = rsqrtf(var + 1e-6f);
    const float* mrow = mod + (size_t)b * (9 * DD);
    const float4 g = *(const float4*)(mrow + gOff + t * 4);
    const float4 e = *(const float4*)(mrow + beOff + t * 4);
    bf16x4v o;
    o[0] = (bf16_t)((v.x - mean) * rstd * (1.0f + g.x) + e.x);
    o[1] = (bf16_t)((v.y - mean) * rstd * (1.0f + g.y) + e.y);
    o[2] = (bf16_t)((v.z - mean) * rstd * (1.0f + g.z) + e.z);
    o[3] = (bf16_t)((v.w - mean) * rstd * (1.0f + g.w) + e.w);
    *(bf16x4v*)(out + (size_t)b * DD + t * 4) = o;
}

// ---------------- generic bf16 MFMA GEMM:  C = epi(A @ W^T + bias) ----------
// A: (M,K) bf16 row-major (lda), W: (N,K) bf16 row-major (ldw).
// global_load_lds staging (m97 2-barrier structure). 4 waves, 2x2 wave grid.
template <int BM, int BN, bool GELU_E, bool RESID, bool WF32, bool WB16>
__global__ __launch_bounds__(256) void k_gemm(
    const bf16_t* __restrict__ A, int lda, int aHeadOff,
    const bf16_t* __restrict__ W, int ldw, int wHeadOff,
    const float* __restrict__ bias, int biasHeadOff,
    float* __restrict__ Cf, bf16_t* __restrict__ Cb, int ldc, int cHeadOff,
    const float* __restrict__ res, int ldres,
    const float* __restrict__ am, int ldam,
    int K) {
    constexpr int BK = 32;
    constexpr int FM = BM / 32, FN = BN / 32;
    constexpr int CA_ = (BM * BK) / 2048;  // 4KB chunks (256 thr x 16B)
    constexpr int CB_ = (BN * BK) / 2048;
    const int z = blockIdx.z;
    A += (size_t)z * aHeadOff;
    W += (size_t)z * wHeadOff;
    const float* biasz = bias ? bias + (size_t)z * biasHeadOff : nullptr;
    const size_t coff = (size_t)z * cHeadOff;

    __shared__ bf16_t As[BM * BK];
    __shared__ bf16_t Bs[BN * BK];

    const int tid = threadIdx.x;
    const int wave = tid >> 6, lane = tid & 63;
    const int m0 = blockIdx.y * BM, n0 = blockIdx.x * BN;
    const int wm = (wave >> 1) * (BM / 2);
    const int wn = (wave & 1) * (BN / 2);

    f32x4 acc[FM][FN];
#pragma unroll
    for (int i = 0; i < FM; ++i)
#pragma unroll
        for (int j = 0; j < FN; ++j) acc[i][j] = {0.f, 0.f, 0.f, 0.f};

    const int lrow = lane & 15;
    const int lk8 = (lane >> 4) * 8;

    for (int k0 = 0; k0 < K; k0 += BK) {
        __syncthreads();  // previous iteration's LDS reads done
#pragma unroll
        for (int c = 0; c < CA_; ++c) {
            const int e = (c * 256 + tid) * 8;
            gload16(A + (size_t)(m0 + (e >> 5)) * lda + k0 + (e & 31), As + e);
        }
#pragma unroll
        for (int c = 0; c < CB_; ++c) {
            const int e = (c * 256 + tid) * 8;
            gload16(W + (size_t)(n0 + (e >> 5)) * ldw + k0 + (e & 31), Bs + e);
        }
        __syncthreads();  // vmcnt(0) drain + visibility

        bf16x8 af[FM], bfr[FN];
#pragma unroll
        for (int i = 0; i < FM; ++i)
            af[i] = *(const bf16x8*)(As + (wm + i * 16 + lrow) * BK + lk8);
#pragma unroll
        for (int j = 0; j < FN; ++j)
            bfr[j] = *(const bf16x8*)(Bs + (wn + j * 16 + lrow) * BK + lk8);
#pragma unroll
        for (int i = 0; i < FM; ++i)
#pragma unroll
            for (int j = 0; j < FN; ++j)
                acc[i][j] = __builtin_amdgcn_mfma_f32_16x16x32_bf16(af[i], bfr[j], acc[i][j], 0, 0, 0);
    }

    // epilogue: C/D layout col=lane&15, row=(lane>>4)*4+e  [verified m89/m91]
    const int r4 = (lane >> 4) * 4;
    const int cc = lane & 15;
#pragma unroll
    for (int i = 0; i < FM; ++i) {
#pragma unroll
        for (int j = 0; j < FN; ++j) {
            const int col = n0 + wn + j * 16 + cc;
            const float bv = biasz ? biasz[col] : 0.0f;
#pragma unroll
            for (int e = 0; e < 4; ++e) {
                const int row = m0 + wm + i * 16 + r4 + e;
                float v = acc[i][j][e] + bv;
                if constexpr (GELU_E) v = 0.5f * v * (1.0f + erff(v * 0.70710678118654752f));
                const size_t cidx = coff + (size_t)row * ldc + col;
                if constexpr (RESID) {
                    Cf[cidx] = res[(size_t)row * ldres + col] + am[(size_t)row * ldam + col] * v;
                } else {
                    if constexpr (WF32) Cf[cidx] = v;
                    if constexpr (WB16) Cb[cidx] = (bf16_t)v;
                }
            }
        }
    }
}

// ---------------- q·bk per head ----------------
__global__ __launch_bounds__(64) void k_qbk(const bf16_t* __restrict__ q,
                                            const float* __restrict__ bk,
                                            float* __restrict__ qbk) {
    const int b = blockIdx.x, lane = threadIdx.x;
#pragma unroll 1
    for (int h = 0; h < NHEAD; ++h) {
        float v = (float)q[(size_t)b * DD + h * 64 + lane] * bk[h * 64 + lane];
#pragma unroll
        for (int o = 32; o > 0; o >>= 1) v += __shfl_xor(v, o, 64);
        if (lane == 0) qbk[(size_t)b * NHEAD + h] = v;
    }
}

// ---------------- fused cross-attention (single ctx pass, online softmax) ---
// score[b,h,l] = (qt[b,h,:]·ctx[b,l,:] + qbk[b,h]) / 8
// mixed[b,h,:] = softmax_l(score) @ ctx[b]
#define CQS 1032  // padded LDS row stride in bf16 elements (+8 -> bank-spread)
__global__ __launch_bounds__(256) void k_ca_fused(
    const bf16_t* __restrict__ qt, const float* __restrict__ qbk,
    const float* __restrict__ ctx, const unsigned char* __restrict__ mask,
    bf16_t* __restrict__ mixed) {
    __shared__ bf16_t qs[16 * CQS];   // 33 KB
    __shared__ bf16_t cs[8 * CQS];    // 16.5 KB
    __shared__ float plds[2 * 16 * 8];
    __shared__ float wex[16 * 8];
    __shared__ float fs[16];
    __shared__ float inv[16];

    const int b = blockIdx.x;
    const int t = threadIdx.x;

    // stage qt (16 x 1024 bf16) -> LDS
    {
        const int h = t >> 4, dl = (t & 15) * 8;
        const bf16_t* src = qt + ((size_t)b * 16 + h) * DD;
#pragma unroll
        for (int u = 0; u < 8; ++u)
            *(bf16x8*)(qs + h * CQS + dl + u * 128) = *(const bf16x8*)(src + dl + u * 128);
    }

    const int hD = t & 15, l3D = (t >> 4) & 7, dq = t >> 7;  // dot mapping
    const int hM = t >> 4, ds16 = t & 15;                    // mix mapping
    float acc[8][8];
#pragma unroll
    for (int j = 0; j < 8; ++j)
#pragma unroll
        for (int e = 0; e < 8; ++e) acc[j][e] = 0.f;

    float mrun = -3.0e38f, den = 0.f;  // live in threads t<16 (head = t)
    const float qb = (t < 16) ? qbk[(size_t)b * NHEAD + t] : 0.f;

    for (int c0 = 0; c0 < LK; c0 += 8) {
        __syncthreads();  // previous chunk's cs/wex reads done
        {                 // stage 8 ctx rows, fp32 -> bf16 (zero-fill beyond LK)
            const int l = t >> 5, d4 = (t & 31) * 4;
            const int lg = c0 + l;
            if (lg < LK) {
                const float* src = ctx + ((size_t)b * LK + lg) * DD;
#pragma unroll
                for (int u = 0; u < 8; ++u) {
                    f32x4 v = *(const f32x4*)(src + d4 + u * 128);
                    bf16x4v o;
                    o[0] = (bf16_t)v.x; o[1] = (bf16_t)v.y;
                    o[2] = (bf16_t)v.z; o[3] = (bf16_t)v.w;
                    *(bf16x4v*)(cs + l * CQS + d4 + u * 128) = o;
                }
            } else {
                bf16x4v o = {(bf16_t)0.f, (bf16_t)0.f, (bf16_t)0.f, (bf16_t)0.f};
#pragma unroll
                for (int u = 0; u < 8; ++u) *(bf16x4v*)(cs + l * CQS + d4 + u * 128) = o;
            }
        }
        __syncthreads();
        {  // partial dots: (h, l, half-of-d)
            float part = 0.f;
            const bf16_t* qr = qs + hD * CQS + dq * 512;
            const bf16_t* cr = cs + l3D * CQS + dq * 512;
#pragma unroll 8
            for (int i = 0; i < 64; ++i) {
                bf16x8 qv = *(const bf16x8*)(qr + i * 8);
                bf16x8 cv = *(const bf16x8*)(cr + i * 8);
#pragma unroll
                for (int e = 0; e < 8; ++e) part += (float)qv[e] * (float)cv[e];
            }
            plds[dq * 128 + hD * 8 + l3D] = part;
        }
        __syncthreads();
        if (t < 16) {  // online softmax update for head t
            float s[8];
            float cm = -3.0e38f;
#pragma unroll
            for (int l = 0; l < 8; ++l) {
                const int lg = c0 + l;
                float sv = -3.0e38f;
                if (lg < LK) {
                    sv = (plds[t * 8 + l] + plds[128 + t * 8 + l] + qb) * 0.125f;
                    if (mask[(size_t)b * LK + lg]) sv = -1.0e9f;
                }
                s[l] = sv;
                cm = fmaxf(cm, sv);
            }
            const float mnew = fmaxf(mrun, cm);
            const float f = __expf(mrun - mnew);
            float wsum = 0.f;
#pragma unroll
            for (int l = 0; l < 8; ++l) {
                const float w = (c0 + l < LK) ? __expf(s[l] - mnew) : 0.f;
                wex[t * 8 + l] = w;
                wsum += w;
            }
            den = den * f + wsum;
            mrun = mnew;
            fs[t] = f;
            inv[t] = 1.0f / den;  // last chunk's value is the final one
        }
        __syncthreads();
        {  // mix accumulate: thread (h, ds16) owns dims d = ds16*8 + j*128
            const float f = fs[hM];
#pragma unroll
            for (int j = 0; j < 8; ++j)
#pragma unroll
                for (int e = 0; e < 8; ++e) acc[j][e] *= f;
#pragma unroll
            for (int l = 0; l < 8; ++l) {
                const float w = wex[hM * 8 + l];
                const bf16_t* cr = cs + l * CQS + ds16 * 8;
#pragma unroll
                for (int j = 0; j < 8; ++j) {
                    bf16x8 cv = *(const bf16x8*)(cr + j * 128);
#pragma unroll
                    for (int e = 0; e < 8; ++e) acc[j][e] += w * (float)cv[e];
                }
            }
        }
    }
    __syncthreads();
    const float iv = inv[hM];
    bf16_t* orow = mixed + ((size_t)b * NHEAD + hM) * DD + ds16 * 8;
#pragma unroll
    for (int j = 0; j < 8; ++j) {
        bf16x8 o;
#pragma unroll
        for (int e = 0; e < 8; ++e) o[e] = (bf16_t)(acc[j][e] * iv);
        *(bf16x8*)(orow + j * 128) = o;
    }
}

// ---------------------------------------------------------------------------
extern "C" void kernel_launch(void* const* d_in, const int* in_sizes, int n_in,
                              void* d_out, int out_size, void* d_ws, size_t ws_size,
                              hipStream_t stream) {
    const float* x = (const float*)d_in[0];
    const float* temb = (const float*)d_in[1];
    const float* ctx = (const float*)d_in[2];
    const unsigned char* mask = (const unsigned char*)d_in[3];
    const float* w_mod = (const float*)d_in[4];
    const float* b_mod = (const float*)d_in[5];
    const float* sa_wv = (const float*)d_in[10];
    const float* sa_bv = (const float*)d_in[11];
    const float* sa_wo = (const float*)d_in[12];
    const float* sa_bo = (const float*)d_in[13];
    const float* ca_wq = (const float*)d_in[14];
    const float* ca_bq = (const float*)d_in[15];
    const float* ca_wk = (const float*)d_in[16];
    const float* ca_bk = (const float*)d_in[17];
    const float* ca_wv = (const float*)d_in[18];
    const float* ca_bv = (const float*)d_in[19];
    const float* ca_wo = (const float*)d_in[20];
    const float* ca_bo = (const float*)d_in[21];
    const float* w1 = (const float*)d_in[22];
    const float* b1 = (const float*)d_in[23];
    const float* w2 = (const float*)d_in[24];
    const float* b2 = (const float*)d_in[25];
    const float* w3 = (const float*)d_in[26];
    const float* b3 = (const float*)d_in[27];

    char* ws = (char*)d_ws;
    size_t off = 0;
    auto alloc = [&](size_t bytes) -> void* {
        void* pp = ws + off;
        off += (bytes + 255) & ~(size_t)255;
        return pp;
    };
    bf16_t* w_mod_b = (bf16_t*)alloc((size_t)9 * DD * DD * 2);
    bf16_t* sa_wv_b = (bf16_t*)alloc((size_t)DD * DD * 2);
    bf16_t* sa_wo_b = (bf16_t*)alloc((size_t)DD * DD * 2);
    bf16_t* ca_wq_b = (bf16_t*)alloc((size_t)DD * DD * 2);
    bf16_t* ca_wv_b = (bf16_t*)alloc((size_t)DD * DD * 2);
    bf16_t* ca_wo_b = (bf16_t*)alloc((size_t)DD * DD * 2);
    bf16_t* wkT_b = (bf16_t*)alloc((size_t)DD * DD * 2);
    bf16_t* w1_b = (bf16_t*)alloc((size_t)DFF_ * DD * 2);
    bf16_t* w2_b = (bf16_t*)alloc((size_t)DFF_ * DFF_ * 2);
    bf16_t* w3_b = (bf16_t*)alloc((size_t)DD * DFF_ * 2);
    bf16_t* tb = (bf16_t*)alloc((size_t)NB * DD * 2);
    float* mod_f = (float*)alloc((size_t)NB * 9 * DD * 4);
    bf16_t* m_b = (bf16_t*)alloc((size_t)NB * DD * 2);
    bf16_t* vsa_b = (bf16_t*)alloc((size_t)NB * DD * 2);
    float* x1 = (float*)alloc((size_t)NB * DD * 4);
    float* x2 = (float*)alloc((size_t)NB * DD * 4);
    bf16_t* q_b = (bf16_t*)alloc((size_t)NB * DD * 2);
    bf16_t* qt_b = (bf16_t*)alloc((size_t)NB * NHEAD * DD * 2);
    float* qbk_f = (float*)alloc((size_t)NB * NHEAD * 4);
    bf16_t* oh_b = (bf16_t*)alloc((size_t)NB * DD * 2);
    bf16_t* h1_b = (bf16_t*)alloc((size_t)NB * DFF_ * 2);
    bf16_t* h2_b = (bf16_t*)alloc((size_t)NB * DFF_ * 2);
    bf16_t* mixed_b = qt_b;  // alias: qt consumed (staged to LDS) before mixed written
    (void)n_in; (void)in_sizes; (void)out_size; (void)ws_size;

    dim3 blk(256);
    // merged weight conversions: 39 units of 1M elements
    ConvTab tab{};
    int nu = 0;
    auto addseg = [&](const float* s, bf16_t* d, int units, int silu) {
        for (int k = 0; k < units; ++k) {
            tab.src[nu] = s + (size_t)k * 1048576;
            tab.dst[nu] = d + (size_t)k * 1048576;
            tab.silu[nu] = silu;
            ++nu;
        }
    };
    addseg(w_mod, w_mod_b, 9, 0);
    addseg(sa_wv, sa_wv_b, 1, 0);
    addseg(sa_wo, sa_wo_b, 1, 0);
    addseg(ca_wq, ca_wq_b, 1, 0);
    addseg(ca_wv, ca_wv_b, 1, 0);
    addseg(ca_wo, ca_wo_b, 1, 0);
    addseg(w1, w1_b, 4, 0);
    addseg(w2, w2_b, 16, 0);
    addseg(w3, w3_b, 4, 0);
    addseg(temb, tb, 1, 1);
    k_conv_all<<<nu * 1024, blk, 0, stream>>>(tab);
    k_transpose_f2b<<<dim3(32, 32), blk, 0, stream>>>(ca_wk, wkT_b);

    // mod = silu(t_emb) @ w_mod.T + b_mod   (fp32 out)
    k_gemm<128, 128, false, false, true, false><<<dim3(72, 8, 1), blk, 0, stream>>>(
        tb, DD, 0, w_mod_b, DD, 0, b_mod, 0, mod_f, nullptr, 9 * DD, 0, nullptr, 0, nullptr, 0, DD);

    // m1 = ln(x)*(1+g1)+be1 ; sa = (m1@wv.T+bv)@wo.T+bo ; x1 = x + a1*sa
    k_ln_mod<<<NB, blk, 0, stream>>>(x, mod_f, 0 * DD, 1 * DD, m_b);
    k_gemm<64, 64, false, false, false, true><<<dim3(16, 16, 1), blk, 0, stream>>>(
        m_b, DD, 0, sa_wv_b, DD, 0, sa_bv, 0, nullptr, vsa_b, DD, 0, nullptr, 0, nullptr, 0, DD);
    k_gemm<64, 64, false, true, true, false><<<dim3(16, 16, 1), blk, 0, stream>>>(
        vsa_b, DD, 0, sa_wo_b, DD, 0, sa_bo, 0, x1, nullptr, DD, 0, x, DD, mod_f + 2 * DD, 9 * DD, DD);

    // m2; q = m2@wq.T+bq; qt[b,h,:] = q_head @ wk_h
    k_ln_mod<<<NB, blk, 0, stream>>>(x1, mod_f, 3 * DD, 4 * DD, m_b);
    k_gemm<64, 64, false, false, false, true><<<dim3(16, 16, 1), blk, 0, stream>>>(
        m_b, DD, 0, ca_wq_b, DD, 0, ca_bq, 0, nullptr, q_b, DD, 0, nullptr, 0, nullptr, 0, DD);
    k_gemm<64, 64, false, false, false, true><<<dim3(16, 16, 16), blk, 0, stream>>>(
        q_b, DD, 64, wkT_b, DD, 64, nullptr, 0, nullptr, qt_b, NHEAD * DD, DD, nullptr, 0, nullptr, 0, 64);
    k_qbk<<<NB, 64, 0, stream>>>(q_b, ca_bk, qbk_f);
    k_ca_fused<<<NB, blk, 0, stream>>>(qt_b, qbk_f, ctx, mask, mixed_b);
    // out_head[b,h*64:+64] = wv_h @ mixed[b,h,:] + bv_h
    k_gemm<64, 64, false, false, false, true><<<dim3(1, 16, 16), blk, 0, stream>>>(
        mixed_b, NHEAD * DD, DD, ca_wv_b, DD, 64 * DD, ca_bv, 64, nullptr, oh_b, DD, 64,
        nullptr, 0, nullptr, 0, DD);
    // ca = out_head@wo.T+bo ; x2 = x1 + a2*ca
    k_gemm<64, 64, false, true, true, false><<<dim3(16, 16, 1), blk, 0, stream>>>(
        oh_b, DD, 0, ca_wo_b, DD, 0, ca_bo, 0, x2, nullptr, DD, 0, x1, DD, mod_f + 5 * DD, 9 * DD, DD);

    // m3; FFN
    k_ln_mod<<<NB, blk, 0, stream>>>(x2, mod_f, 6 * DD, 7 * DD, m_b);
    k_gemm<64, 128, true, false, false, true><<<dim3(32, 16, 1), blk, 0, stream>>>(
        m_b, DD, 0, w1_b, DD, 0, b1, 0, nullptr, h1_b, DFF_, 0, nullptr, 0, nullptr, 0, DD);
    k_gemm<64, 128, true, false, false, true><<<dim3(32, 16, 1), blk, 0, stream>>>(
        h1_b, DFF_, 0, w2_b, DFF_, 0, b2, 0, nullptr, h2_b, DFF_, 0, nullptr, 0, nullptr, 0, DFF_);
    // out = x2 + a3 * (h2@w3.T + b3)
    k_gemm<64, 64, false, true, true, false><<<dim3(16, 16, 1), blk, 0, stream>>>(
        h2_b, DFF_, 0, w3_b, DFF_, 0, b3, 0, (float*)d_out, nullptr, DD, 0, x2, DD,
        mod_f + 8 * DD, 9 * DD, DFF_);
}